// Round 5
// baseline (976.582 us; speedup 1.0000x reference)
//
#include <hip/hip_runtime.h>
#include <stdint.h>
#include <math.h>

// ---------------------------------------------------------------------------
// PathIntegration: h = relu(actions@w1+b1); trans = (h@w2+b2) -> [B,T,D,D]
// s_{t+1} = l2norm(relu(s_t @ trans_t)); output ys[B,T,D] (f32)
// B=32 T=512 A=64 H=256 D=128
// Round 13 = round 12 with the coherence scheme swapped (ONLY change):
//  - trans producer stores:  global_store_dwordx2 ... sc1 nt  (device-scope
//    write-through; no dirty L2, no pollution)
//  - trans consumer loads:   global_load_dwordx4 ... sc1 nt   (device-scope
//    read; immune to stale L2 from buffer reuse)
//  - BOTH __threadfence() calls removed (they cost a buffer_wbl2 per gemm
//    tile (4096x, flushing the XCD's dirty L2) + buffer_inv per rec chunk;
//    r12 PMC showed all pipes <25% busy with an 18us chunk period -> the
//    fences, not the work, set the period)
//  - flag atomicAdds are RELEASE (wbl2 now ~free: nothing dirty); ordering:
//    __syncthreads' implicit vmcnt(0) retires sc1 stores device-visible
//    before the flag add issues.
// Everything else byte-identical to round 12 (clean A/B).
// ---------------------------------------------------------------------------

typedef _Float16 f16x8 __attribute__((ext_vector_type(8)));
typedef _Float16 f16x4 __attribute__((ext_vector_type(4)));
typedef float    f32x4 __attribute__((ext_vector_type(4)));

#define B_  32
#define T_  512
#define A_  64
#define H_  256
#define D_  128
#define N_  (D_ * D_)      // 16384
#define M_  (B_ * T_)      // 16384
#define TC_ 16
#define NCH_ (T_ / TC_)    // 32
#define MT_ 2              // 256-row groups per chunk
#define CHB ((size_t)TC_ << 20)   // 16 MB per chunk buffer

__device__ inline void glds(const void* g, void* l) {
  __builtin_amdgcn_global_load_lds(
      (__attribute__((address_space(1))) void*)g,
      (__attribute__((address_space(3))) void*)l, 16, 0, 0);
}

// ---------------- prep: w2 cast+transpose+permute, h, flags ------------------
// w2t permute: orig col n -> T entry (i=n>>7, j=n&127); position
// p = (j>>4)<<11 | (i>>5)<<9 | ((i>>3)&3)<<7 | (j&15)<<3 | (i&7)
// per (b,t) 32KB slab is wave-major, frag-major, lane-direct.
__global__ __launch_bounds__(256) void prep_kernel(
    const float* __restrict__ w2, _Float16* __restrict__ w2t,
    const float* __restrict__ actions, const float* __restrict__ w1,
    const float* __restrict__ b1, _Float16* __restrict__ h16,
    unsigned* __restrict__ flags) {
  __shared__ __align__(16) char psm[40960];
  const int t = threadIdx.x;
  if (blockIdx.x < 1024) {
    // ---------------- w2cast part ----------------
    if (blockIdx.x == 0) {
      #pragma unroll
      for (int i = 0; i < 4; ++i) flags[t + i * 256] = 0u;
    }
    float (*tile)[65] = (float(*)[65])psm;
    const int n0 = (blockIdx.x & 255) * 64, k0 = (blockIdx.x >> 8) * 64;
    const int nn = t & 63, kg = t >> 6;
    #pragma unroll
    for (int r = 0; r < 16; ++r) {
      int k = kg * 16 + r;
      tile[k][nn] = w2[(size_t)(k0 + k) * N_ + n0 + nn];
    }
    __syncthreads();
    const int kk = t & 63, ng = t >> 6;
    #pragma unroll
    for (int r = 0; r < 16; ++r) {
      int n = ng * 16 + r;
      int ngl = n0 + n;
      int i = ngl >> 7, j = ngl & 127;
      int p = ((j >> 4) << 11) | ((i >> 5) << 9) | (((i >> 3) & 3) << 7)
            | ((j & 15) << 3) | (i & 7);
      w2t[(size_t)p * H_ + k0 + kk] = (_Float16)tile[kk][n];
    }
  } else {
    // ---------------- h = relu(actions@w1+b1) ----------------
    float* w1s = (float*)psm;             // 32*256 f32
    float* acts = (float*)(psm + 32768);  // 32*64 f32
    const size_t row0 = (size_t)(blockIdx.x - 1024) * 32;

    #pragma unroll
    for (int i = 0; i < 8; ++i) acts[t + i * 256] = actions[row0 * A_ + t + i * 256];

    float acc[32];
    float bj = b1[t];
    #pragma unroll
    for (int r = 0; r < 32; ++r) acc[r] = bj;

    for (int half = 0; half < 2; ++half) {
      __syncthreads();
      #pragma unroll
      for (int i = 0; i < 32; ++i) w1s[t + i * 256] = w1[half * 32 * 256 + t + i * 256];
      __syncthreads();
      #pragma unroll
      for (int r = 0; r < 32; ++r) {
        float a = acc[r];
        #pragma unroll
        for (int k = 0; k < 32; ++k)
          a += acts[r * 64 + half * 32 + k] * w1s[k * 256 + t];
        acc[r] = a;
      }
    }
    #pragma unroll
    for (int r = 0; r < 32; ++r)
      h16[(row0 + r) * H_ + t] = (_Float16)fmaxf(acc[r], 0.f);
  }
}

// ---------------- fused pipeline: rec blocks 0..31, gemm 32..255 -------------
__global__ __launch_bounds__(512, 2) void fused_kernel(
    const _Float16* __restrict__ h16, const _Float16* __restrict__ w2t,
    const float* __restrict__ b2, _Float16* __restrict__ tbase,
    const float* __restrict__ init_s, float* __restrict__ out,
    float* __restrict__ dummyws, unsigned* __restrict__ flags, int NB) {

  // gemm blocks use all 64KB (A/B double-buffer). rec blocks (disjoint)
  // overlap: sb0 @0 (256B), sb1 @256 (256B), red @512 (32B).
  __shared__ __align__(16) char smem[65536];
  const int tid  = threadIdx.x;
  const int lane = tid & 63;
  const int w    = tid >> 6;

  if (blockIdx.x < 32) {
    // ======================= recurrence block ===============================
    const int b  = blockIdx.x;
    const int n16 = lane & 15, q = lane >> 4;
    const int col = w * 16 + n16;
    float* red = (float*)(smem + 512);
    _Float16* sb0p = (_Float16*)smem;

    // ---- init s_0 once (state persists in LDS/regs across chunks) ----
    float v0 = 0.f;
    if (tid < 128) {
      v0 = init_s[tid];
      float ss = v0 * v0;
      #pragma unroll
      for (int off = 32; off > 0; off >>= 1) ss += __shfl_xor(ss, off);
      if (lane == 0) red[w] = ss;
    }
    __syncthreads();
    if (tid < 128) {
      float inv0 = 1.f / fmaxf(sqrtf(red[0] + red[1]), 1e-12f);
      sb0p[tid] = (_Float16)(v0 * inv0);
    }
    __syncthreads();
    float uprev = (float)sb0p[col];

    const unsigned sbase = (unsigned)(size_t)(__attribute__((address_space(3))) char*)smem;
    const unsigned aA0 = sbase + 0   + q * 16;   // step par 0 reads sb0
    const unsigned aA1 = sbase + 256 + q * 16;   // step par 1 reads sb1
    const unsigned aW0 = sbase + 256 + col * 2;  // step par 0 writes sb1
    const unsigned aW1 = sbase + 0   + col * 2;  // step par 1 writes sb0
    float* outb = out + (size_t)b * T_ * D_ + col;
    float* dsink = dummyws + b * 128 + col;
    const int grp = b >> 4;

    f16x8 ring[4][4];
    const f32x4 zf = {0.f, 0.f, 0.f, 0.f};

#define LDSLOT(S, P)                                                          \
    asm volatile("global_load_dwordx4 %0, %4, off sc1 nt\n\t"                 \
                 "global_load_dwordx4 %1, %4, off offset:1024 sc1 nt\n\t"     \
                 "global_load_dwordx4 %2, %4, off offset:2048 sc1 nt\n\t"     \
                 "global_load_dwordx4 %3, %4, off offset:3072 sc1 nt"         \
                 : "=v"(ring[S][0]), "=v"(ring[S][1]),                        \
                   "=v"(ring[S][2]), "=v"(ring[S][3])                         \
                 : "v"(P) : "memory")

#define STEP(TT, PAR, SPAR, WAITN)                                            \
    {                                                                         \
      const int tt = (TT);                                                    \
      f16x8 A0, A1, A2, A3;                                                   \
      asm volatile(                                                           \
        "s_waitcnt vmcnt(" #WAITN ")\n\t"                                     \
        "ds_read_b128 %0, %8 offset:0\n\t"                                    \
        "ds_read_b128 %1, %8 offset:64\n\t"                                   \
        "ds_read_b128 %2, %8 offset:128\n\t"                                  \
        "ds_read_b128 %3, %8 offset:192\n\t"                                  \
        "s_waitcnt lgkmcnt(0)"                                                \
        : "=v"(A0), "=v"(A1), "=v"(A2), "=v"(A3),                             \
          "+v"(ring[PAR][0]), "+v"(ring[PAR][1]),                             \
          "+v"(ring[PAR][2]), "+v"(ring[PAR][3])                              \
        : "v"(aA##SPAR) : "memory");                                          \
      f32x4 c0 = __builtin_amdgcn_mfma_f32_16x16x32_f16(A0, ring[PAR][0], zf, 0, 0, 0); \
      f32x4 c1 = __builtin_amdgcn_mfma_f32_16x16x32_f16(A1, ring[PAR][1], zf, 0, 0, 0); \
      f32x4 c2 = __builtin_amdgcn_mfma_f32_16x16x32_f16(A2, ring[PAR][2], zf, 0, 0, 0); \
      f32x4 c3 = __builtin_amdgcn_mfma_f32_16x16x32_f16(A3, ring[PAR][3], zf, 0, 0, 0); \
      f32x4 cs = __builtin_amdgcn_mfma_f32_16x16x32_f16(A0, A0, zf, 0, 0, 0); \
      cs = __builtin_amdgcn_mfma_f32_16x16x32_f16(A1, A1, cs, 0, 0, 0);       \
      cs = __builtin_amdgcn_mfma_f32_16x16x32_f16(A2, A2, cs, 0, 0, 0);       \
      cs = __builtin_amdgcn_mfma_f32_16x16x32_f16(A3, A3, cs, 0, 0, 0);       \
      const char* gd = Gw + (size_t)((tt + 4) & 15) * 32768;                  \
      LDSLOT(PAR, gd);                                                        \
      float ssp = cs[0];                                                      \
      float inv = 1.f / fmaxf(sqrtf(ssp), 1e-12f);                            \
      float y = c0[0] + c1[0] + c2[0] + c3[0];                                \
      float un = fmaxf(y, 0.f) * inv;                                         \
      float o = uprev * inv;                                                  \
      uprev = un;                                                             \
      _Float16 hv = (_Float16)un;                                             \
      const int gt = t0 + tt;                                                 \
      float* gp = (gt > 0) ? (outb + (size_t)(gt - 1) * D_) : dsink;          \
      asm volatile("ds_write_b16 %0, %1\n\t"                                  \
                   "global_store_dword %2, %3, off"                           \
                   :: "v"(aW##SPAR), "v"(hv), "v"(gp), "v"(o) : "memory");    \
      asm volatile("s_waitcnt lgkmcnt(0)\n\ts_barrier" ::: "memory");         \
    }

    for (int c = 0; c < NCH_; ++c) {
      if (tid == 0) {
        while (__hip_atomic_load(&flags[c * MT_ + grp], __ATOMIC_RELAXED,
                                 __HIP_MEMORY_SCOPE_AGENT) < 64u)
          __builtin_amdgcn_s_sleep(8);
        // no fence: slab loads are sc1 (device-scope) -> no stale L2 risk
      }
      __syncthreads();

      const char* trans = (const char*)tbase + (size_t)(c % NB) * CHB;
      const char* Gw = trans + (size_t)b * TC_ * 32768 + w * 4096 + lane * 16;
      const int t0 = c * TC_;

      LDSLOT(0, Gw + 0 * 32768);
      LDSLOT(1, Gw + 1 * 32768);
      LDSLOT(2, Gw + 2 * 32768);
      LDSLOT(3, Gw + 3 * 32768);

      STEP(0, 0, 0, 12)
      STEP(1, 1, 1, 13)
      STEP(2, 2, 0, 14)
      STEP(3, 3, 1, 15)
      for (int tt0 = 4; tt0 < TC_; tt0 += 4) {
        STEP(tt0,     0, 0, 16)
        STEP(tt0 + 1, 1, 1, 16)
        STEP(tt0 + 2, 2, 0, 16)
        STEP(tt0 + 3, 3, 1, 16)
      }
      asm volatile("s_waitcnt vmcnt(0)" ::: "memory");
      __syncthreads();   // all waves' loads drained before releasing buffer
      if (tid == 0)
        __hip_atomic_fetch_add(&flags[512 + c], 1u, __ATOMIC_RELEASE,
                               __HIP_MEMORY_SCOPE_AGENT);
    }
#undef STEP
#undef LDSLOT

    // ---- final epilogue: state in sb0; write out[T-1] ----
    {
      float x = 0.f;
      if (lane < 16) x = (float)((_Float16*)smem)[col];
      float ss2 = x * x;
      ss2 += __shfl_xor(ss2, 1);
      ss2 += __shfl_xor(ss2, 2);
      ss2 += __shfl_xor(ss2, 4);
      ss2 += __shfl_xor(ss2, 8);
      if (lane == 0) red[w] = ss2;
      __syncthreads();
      float tot = 0.f;
      #pragma unroll
      for (int g = 0; g < 8; ++g) tot += red[g];
      float inv = 1.f / fmaxf(sqrtf(tot), 1e-12f);
      if (lane < 16) outb[(size_t)(T_ - 1) * D_] = uprev * inv;
    }
  } else {
    // ======================= streaming gemm producer ========================
    _Float16* smA[2] = {(_Float16*)smem, (_Float16*)(smem + 32768)};
    _Float16* smB[2] = {(_Float16*)(smem + 16384), (_Float16*)(smem + 49152)};

    const int wm = w >> 2, wn = w & 3;          // 2x4 wave grid: 128m x 64n
    const int fm = lane & 15, fq = lane >> 4;
    const int sw = fq ^ ((fm >> 1) & 3);        // bank-conflict deswizzle
    const f32x4 zero = {0.f, 0.f, 0.f, 0.f};

    const int cA0 = tid, cA1 = tid + 512;
    const int rA0 = cA0 >> 2, rA1 = cA1 >> 2;
    const int kA0 = (cA0 & 3) ^ ((rA0 >> 1) & 3);  // swizzled k-slot (staging)
    const int kA1 = (cA1 & 3) ^ ((rA1 >> 1) & 3);

    const int TOT = NCH_ * 128;                 // 4096 tiles (128/chunk)

    for (int job = (int)blockIdx.x - 32; job < TOT; job += 224) {
      const int g    = job >> 7;
      const int tile = job & 127;
      const int bn = tile & 63;
      const int bm = tile >> 6;

      _Float16* trans = (_Float16*)((char*)tbase + (size_t)(g % NB) * CHB);
      const int t0g = g * TC_;

      const int mc0 = bm * 256 + rA0, mc1 = bm * 256 + rA1;
      const int bb0 = mc0 >> 4, bb1 = mc1 >> 4;
      const _Float16* gA0 = h16 + ((size_t)bb0 * T_ + t0g + (mc0 & 15)) * H_ + kA0 * 8;
      const _Float16* gA1 = h16 + ((size_t)bb1 * T_ + t0g + (mc1 & 15)) * H_ + kA1 * 8;
      const _Float16* gB0 = w2t + ((size_t)bn * 256 + rA0) * H_ + kA0 * 8;
      const _Float16* gB1 = w2t + ((size_t)bn * 256 + rA1) * H_ + kA1 * 8;
      _Float16* lA0[2] = {&smA[0][cA0 * 8], &smA[1][cA0 * 8]};
      _Float16* lA1[2] = {&smA[0][cA1 * 8], &smA[1][cA1 * 8]};
      _Float16* lB0[2] = {&smB[0][cA0 * 8], &smB[1][cA0 * 8]};
      _Float16* lB1[2] = {&smB[0][cA1 * 8], &smB[1][cA1 * 8]};

      f32x4 acc[8][4];
      #pragma unroll
      for (int i = 0; i < 8; ++i)
        #pragma unroll
        for (int j = 0; j < 4; ++j) acc[i][j] = zero;

      // prologue: stage kt=0 into half 0
      glds(gA0, lA0[0]);
      glds(gA1, lA1[0]);
      glds(gB0, lB0[0]);
      glds(gB1, lB1[0]);

      #pragma unroll
      for (int kt = 0; kt < 8; ++kt) {
        __syncthreads();   // implicit vmcnt(0): glds(kt) landed; half free
        if (kt < 7) {
          const int h2 = (kt + 1) & 1;
          glds(gA0 + (kt + 1) * 32, lA0[h2]);
          glds(gA1 + (kt + 1) * 32, lA1[h2]);
          glds(gB0 + (kt + 1) * 32, lB0[h2]);
          glds(gB1 + (kt + 1) * 32, lB1[h2]);
        }
        const int hh = kt & 1;
        const _Float16* bA = smA[hh];
        const _Float16* bB = smB[hh];
        f16x8 af[8], bf[4];
        #pragma unroll
        for (int mt = 0; mt < 8; ++mt)
          af[mt] = *(const f16x8*)&bA[(wm * 128 + mt * 16 + fm) * 32 + sw * 8];
        #pragma unroll
        for (int nt = 0; nt < 4; ++nt)
          bf[nt] = *(const f16x8*)&bB[(wn * 64 + nt * 16 + fm) * 32 + sw * 8];
        #pragma unroll
        for (int mt = 0; mt < 8; ++mt)
          #pragma unroll
          for (int nt = 0; nt < 4; ++nt)
            acc[mt][nt] = __builtin_amdgcn_mfma_f32_16x16x32_f16(bf[nt], af[mt], acc[mt][nt], 0, 0, 0);
      }

      // bias decode (b2 direct, L2-hit) — hoisted before the gating wait
      const int colbase = bn * 256 + wn * 64;
      float bias[4][4];
      #pragma unroll
      for (int nt = 0; nt < 4; ++nt) {
        #pragma unroll
        for (int j = 0; j < 4; ++j) {
          int p = colbase + nt * 16 + fq * 4 + j;
          int ii = ((p >> 9) & 3) * 32 + ((p >> 7) & 3) * 8 + (p & 7);
          int jj = (p >> 11) * 16 + ((p >> 3) & 15);
          bias[nt][j] = b2[ii * 128 + jj];
        }
      }

      // back-pressure (buffer reuse) — gate only the overwrite
      if (g >= NB) {
        if (tid == 0) {
          while (__hip_atomic_load(&flags[512 + g - NB], __ATOMIC_RELAXED,
                                   __HIP_MEMORY_SCOPE_AGENT) < 32u)
            __builtin_amdgcn_s_sleep(8);
        }
        __syncthreads();
      }

      // epilogue: swapped-operand layout -> lane fm holds rows, 4 consec cols
      // stores are sc1 nt: device-visible at vmcnt(0), no L2 dirty/pollution
      #pragma unroll
      for (int nt = 0; nt < 4; ++nt) {
        const int cb = nt * 16 + fq * 4;
        #pragma unroll
        for (int mt = 0; mt < 8; ++mt) {
          const long row = bm * 256 + wm * 128 + mt * 16 + fm;
          f16x4 v;
          #pragma unroll
          for (int j = 0; j < 4; ++j)
            v[j] = (_Float16)(acc[mt][nt][j] + bias[nt][j]);
          _Float16* sp = &trans[row * (long)N_ + colbase + cb];
          asm volatile("global_store_dwordx2 %0, %1, off sc1 nt"
                       :: "v"(sp), "v"(v) : "memory");
        }
      }
      __syncthreads();   // implicit vmcnt(0): sc1 stores device-visible
      if (tid == 0) {
        __hip_atomic_fetch_add(&flags[g * MT_ + bm], 1u, __ATOMIC_RELEASE,
                               __HIP_MEMORY_SCOPE_AGENT);
      }
    }
  }
}

// ---------------------------------------------------------------------------
extern "C" void kernel_launch(void* const* d_in, const int* in_sizes, int n_in,
                              void* d_out, int out_size, void* d_ws, size_t ws_size,
                              hipStream_t stream) {
  const float* actions = (const float*)d_in[0];   // [32,512,64]
  const float* init_s  = (const float*)d_in[1];   // [128]
  const float* w1      = (const float*)d_in[2];   // [64,256]
  const float* b1      = (const float*)d_in[3];   // [256]
  const float* w2      = (const float*)d_in[4];   // [256,16384]
  const float* b2      = (const float*)d_in[5];   // [16384]
  float* out = (float*)d_out;                     // [32,512,128]

  uint8_t* ws = (uint8_t*)d_ws;
  _Float16* w2t = (_Float16*)ws;                          // 8 MB
  _Float16* h16 = (_Float16*)(ws + ((size_t)8 << 20));    // 8 MB
  const size_t tb_off = (size_t)16 << 20;
  _Float16* tbase = (_Float16*)(ws + tb_off);

  // deepest chunk ring that fits (aux = 64KB dummy sink + 4KB flags after it)
  const size_t aux = 65536 + 4096;
  int NB = 2;
  if (tb_off + 4 * CHB + aux <= ws_size) NB = 4;
  else if (tb_off + 3 * CHB + aux <= ws_size) NB = 3;

  float*    dummyws = (float*)(ws + tb_off + (size_t)NB * CHB);
  unsigned* flags   = (unsigned*)(ws + tb_off + (size_t)NB * CHB + 65536);

  prep_kernel<<<1536, 256, 0, stream>>>(w2, w2t, actions, w1, b1, h16, flags);
  fused_kernel<<<256, 512, 0, stream>>>(h16, w2t, b2, tbase, init_s,
                                        out, dummyws, flags, NB);
}

// Round 6
// 922.618 us; speedup vs baseline: 1.0585x; 1.0585x over previous
//
#include <hip/hip_runtime.h>
#include <stdint.h>
#include <math.h>

// ---------------------------------------------------------------------------
// PathIntegration: h = relu(actions@w1+b1); trans = (h@w2+b2) -> [B,T,D,D]
// s_{t+1} = l2norm(relu(s_t @ trans_t)); output ys[B,T,D] (f32)
// B=32 T=512 A=64 H=256 D=128
// Round 14: column-split recurrence K=4 (attack the measured wall: rec trans
// stream = 23 GB/s/CU = per-CU HBM ceiling; 32 CUs pulled 512 MB -> ~580us).
//  - 128 rec blocks: (b,p) reads slab bytes [p*8192,(p+1)*8192) (waves 2p,2p+1
//    of the wave-major slab layout = T cols [32p,32p+32)), computes its 32
//    y-cols with the same broadcast-MFMA math (bit-identical f16 path).
//  - per-step exchange of 32-col u-slices via SELF-FLAGGING sign-parity
//    protocol: relu output >= 0 -> fp16 sign bit = validity token. 4 slots
//    (t&3), sign-set iff ((t>>2)&1)==0 -> stale always mismatches. Publish =
//    fire-and-forget sc0 sc1 short stores; wave 0 polls (own vmcnt only,
//    compute waves keep static ring vmcnt schedule). No fences on the path.
//  - roles per rec block: wave0 = poll/exchange, waves 1,2 = compute (4 KB
//    slab slice each, ring[4][4], vmcnt 12/14/16/18 then 18), waves 3-7 idle.
//  - raw s_barrier (B1 lgkm-fenced, B2 plain) per step; __syncthreads only at
//    chunk boundaries (its vmcnt(0) drain is wanted there).
//  - gemm: r12 scheme verbatim (plain stores + per-tile threadfence + flag),
//    128 producer blocks, flags per (chunk, bm, p-group of 16 col-tiles).
//  - all spin loops have iteration caps (bounded wrong-exit beats a hang).
// ---------------------------------------------------------------------------

typedef _Float16 f16x8 __attribute__((ext_vector_type(8)));
typedef _Float16 f16x4 __attribute__((ext_vector_type(4)));
typedef float    f32x4 __attribute__((ext_vector_type(4)));

#define B_  32
#define T_  512
#define A_  64
#define H_  256
#define D_  128
#define N_  (D_ * D_)      // 16384
#define M_  (B_ * T_)      // 16384
#define TC_ 16
#define NCH_ (T_ / TC_)    // 32
#define CHB ((size_t)TC_ << 20)   // 16 MB per chunk buffer
#define SPINCAP (1 << 22)

__device__ inline void glds(const void* g, void* l) {
  __builtin_amdgcn_global_load_lds(
      (__attribute__((address_space(1))) void*)g,
      (__attribute__((address_space(3))) void*)l, 16, 0, 0);
}

// ---------------- prep: w2 cast+transpose+permute, h, flags, xch -------------
// w2t permute: orig col n -> T entry (i=n>>7, j=n&127); position
// p = (j>>4)<<11 | (i>>5)<<9 | ((i>>3)&3)<<7 | (j&15)<<3 | (i&7)
// per (b,t) 32KB slab is wave-major (j>>4), frag-major, lane-direct.
__global__ __launch_bounds__(256) void prep_kernel(
    const float* __restrict__ w2, _Float16* __restrict__ w2t,
    const float* __restrict__ actions, const float* __restrict__ w1,
    const float* __restrict__ b1, _Float16* __restrict__ h16,
    unsigned* __restrict__ flags, unsigned* __restrict__ xch) {
  __shared__ __align__(16) char psm[40960];
  const int t = threadIdx.x;
  if (blockIdx.x < 1024) {
    if (blockIdx.x == 0) {
      #pragma unroll
      for (int i = 0; i < 4; ++i) flags[t + i * 256] = 0u;
      // xch: 32 b x 4 slots x 128 f16 = 8192 dwords. slot = (d>>6)&3.
      // slot0 init sign-SET-all (stale for t=4 which expects CLEAR);
      // slots 1-3 init CLEAR (stale for t=1..3 which expect SET).
      #pragma unroll
      for (int i = 0; i < 32; ++i) {
        int d = t + i * 256;
        xch[d] = (((d >> 6) & 3) == 0) ? 0xFFFFFFFFu : 0u;
      }
    }
    float (*tile)[65] = (float(*)[65])psm;
    const int n0 = (blockIdx.x & 255) * 64, k0 = (blockIdx.x >> 8) * 64;
    const int nn = t & 63, kg = t >> 6;
    #pragma unroll
    for (int r = 0; r < 16; ++r) {
      int k = kg * 16 + r;
      tile[k][nn] = w2[(size_t)(k0 + k) * N_ + n0 + nn];
    }
    __syncthreads();
    const int kk = t & 63, ng = t >> 6;
    #pragma unroll
    for (int r = 0; r < 16; ++r) {
      int n = ng * 16 + r;
      int ngl = n0 + n;
      int i = ngl >> 7, j = ngl & 127;
      int p = ((j >> 4) << 11) | ((i >> 5) << 9) | (((i >> 3) & 3) << 7)
            | ((j & 15) << 3) | (i & 7);
      w2t[(size_t)p * H_ + k0 + kk] = (_Float16)tile[kk][n];
    }
  } else {
    float* w1s = (float*)psm;             // 32*256 f32
    float* acts = (float*)(psm + 32768);  // 32*64 f32
    const size_t row0 = (size_t)(blockIdx.x - 1024) * 32;

    #pragma unroll
    for (int i = 0; i < 8; ++i) acts[t + i * 256] = actions[row0 * A_ + t + i * 256];

    float acc[32];
    float bj = b1[t];
    #pragma unroll
    for (int r = 0; r < 32; ++r) acc[r] = bj;

    for (int half = 0; half < 2; ++half) {
      __syncthreads();
      #pragma unroll
      for (int i = 0; i < 32; ++i) w1s[t + i * 256] = w1[half * 32 * 256 + t + i * 256];
      __syncthreads();
      #pragma unroll
      for (int r = 0; r < 32; ++r) {
        float a = acc[r];
        #pragma unroll
        for (int k = 0; k < 32; ++k)
          a += acts[r * 64 + half * 32 + k] * w1s[k * 256 + t];
        acc[r] = a;
      }
    }
    #pragma unroll
    for (int r = 0; r < 32; ++r)
      h16[(row0 + r) * H_ + t] = (_Float16)fmaxf(acc[r], 0.f);
  }
}

// ---------------- fused pipeline: rec blocks 0..127, gemm 128..255 -----------
__global__ __launch_bounds__(512, 2) void fused_kernel(
    const _Float16* __restrict__ h16, const _Float16* __restrict__ w2t,
    const float* __restrict__ b2, _Float16* __restrict__ tbase,
    const float* __restrict__ init_s, float* __restrict__ out,
    float* __restrict__ dummyws, unsigned* __restrict__ flags,
    unsigned short* __restrict__ xch, int NB) {

  // gemm blocks use all 64KB (A/B double-buffer). rec blocks (disjoint)
  // overlap: sb @0 (256B), red @512 (32B).
  __shared__ __align__(16) char smem[65536];
  const int tid  = threadIdx.x;
  const int lane = tid & 63;
  const int w    = tid >> 6;

  if (blockIdx.x < 128) {
    // ======================= recurrence block (b, p) =======================
    const int b = blockIdx.x & 31, p = blockIdx.x >> 5;
    const int n16 = lane & 15, q = lane >> 4;
    const bool act = (w == 1 || w == 2);
    const int wv = (w - 1) & 1;               // 0/1 for act waves
    const int col = p * 32 + wv * 16 + n16;   // this wave's 16 cols
    const int W = 2 * p + wv;                 // slab wave-slice index
    float* red = (float*)(smem + 512);
    _Float16* sb = (_Float16*)smem;

    // ---- init u_0 = l2norm(init_s), full copy in sb (redundant per block) --
    float v0 = 0.f;
    if (tid < 128) {
      v0 = init_s[tid];
      float ss = v0 * v0;
      #pragma unroll
      for (int off = 32; off > 0; off >>= 1) ss += __shfl_xor(ss, off);
      if (lane == 0) red[w] = ss;
    }
    __syncthreads();
    if (tid < 128) {
      float inv0 = 1.f / fmaxf(sqrtf(red[0] + red[1]), 1e-12f);
      sb[tid] = (_Float16)(v0 * inv0);
    }
    __syncthreads();
    float unreg = act ? (float)sb[col] : 0.f;

    const unsigned sbase = (unsigned)(size_t)(__attribute__((address_space(3))) char*)smem;
    const unsigned aA    = sbase + q * 16;          // s-broadcast frag reads
    const unsigned aOwn  = sbase + (unsigned)(p * 32 + wv * 16 + n16) * 2;
    unsigned short* xb = xch + b * 512;             // 4 slots x 128 f16
    float* outb  = out + (size_t)b * T_ * D_ + col;
    float* dsink = dummyws + b * 128 + (act ? col : 0);
    // wave0 poll lanes: l<48 -> partner kk3 = l>>4, dword (l&15) of its slice
    const int kk3 = lane >> 4;
    const int pp  = kk3 + (kk3 >= p);               // partner p' (for l<48)
    const unsigned pdw = (unsigned)(pp * 64 + (lane & 15) * 4);  // bytes in slot
    const unsigned psb = sbase + pdw;

    f16x8 ring[4][4];
    const f32x4 zf = {0.f, 0.f, 0.f, 0.f};
    const char* Gw = nullptr;

#define LDSLOT(S, P)                                                          \
    asm volatile("global_load_dwordx4 %0, %4, off\n\t"                        \
                 "global_load_dwordx4 %1, %4, off offset:1024\n\t"            \
                 "global_load_dwordx4 %2, %4, off offset:2048\n\t"            \
                 "global_load_dwordx4 %3, %4, off offset:3072"                \
                 : "=v"(ring[S][0]), "=v"(ring[S][1]),                        \
                   "=v"(ring[S][2]), "=v"(ring[S][3])                         \
                 : "v"(P) : "memory")

#define STEP(TT, WAITN)                                                       \
    {                                                                         \
      constexpr int SLOT  = (TT) & 3;                                         \
      constexpr int NSLOT = ((TT) + 1) & 3;                                   \
      constexpr unsigned EXPS = ((((TT) >> 2) & 1) == 0) ? 1u : 0u;           \
      constexpr bool SETN = ((((TT) + 1) >> 2) & 1) == 0;                     \
      if (w == 0) {                                                           \
        if (!((TT) == 0 && c == 0)) {                                         \
          const unsigned* pga =                                               \
              (const unsigned*)((const char*)xb + SLOT * 256 + pdw);          \
          unsigned v = 0; int gd = 0; const bool need = (lane < 48);          \
          for (;;) {                                                          \
            asm volatile("global_load_dword %0, %1, off sc0 sc1\n\t"          \
                         "s_waitcnt vmcnt(0)" : "=v"(v) : "v"(pga)            \
                         : "memory");                                         \
            bool ok = !need ||                                                \
                      ((((v >> 15) & 1u) == EXPS) && (((v >> 31) & 1u) == EXPS)); \
            if (__all(ok) || ++gd > SPINCAP) break;                           \
          }                                                                   \
          if (need) {                                                         \
            v &= 0x7fff7fffu;                                                 \
            asm volatile("ds_write_b32 %0, %1" :: "v"(psb), "v"(v)            \
                         : "memory");                                         \
          }                                                                   \
        }                                                                     \
      } else if (act && q == 0) {                                             \
        _Float16 hf = (_Float16)unreg;                                        \
        unsigned hb = (unsigned)__builtin_bit_cast(unsigned short, hf);       \
        asm volatile("ds_write_b16 %0, %1" :: "v"(aOwn), "v"(hb) : "memory"); \
      }                                                                       \
      asm volatile("s_waitcnt lgkmcnt(0)\n\ts_barrier" ::: "memory");         \
      if (act) {                                                              \
        f16x8 A0, A1, A2, A3;                                                 \
        asm volatile(                                                         \
          "s_waitcnt vmcnt(" #WAITN ")\n\t"                                   \
          "ds_read_b128 %0, %8 offset:0\n\t"                                  \
          "ds_read_b128 %1, %8 offset:64\n\t"                                 \
          "ds_read_b128 %2, %8 offset:128\n\t"                                \
          "ds_read_b128 %3, %8 offset:192\n\t"                                \
          "s_waitcnt lgkmcnt(0)"                                              \
          : "=v"(A0), "=v"(A1), "=v"(A2), "=v"(A3),                           \
            "+v"(ring[SLOT][0]), "+v"(ring[SLOT][1]),                         \
            "+v"(ring[SLOT][2]), "+v"(ring[SLOT][3])                          \
          : "v"(aA) : "memory");                                              \
        f32x4 c0 = __builtin_amdgcn_mfma_f32_16x16x32_f16(A0, ring[SLOT][0], zf, 0, 0, 0); \
        f32x4 c1 = __builtin_amdgcn_mfma_f32_16x16x32_f16(A1, ring[SLOT][1], zf, 0, 0, 0); \
        f32x4 c2 = __builtin_amdgcn_mfma_f32_16x16x32_f16(A2, ring[SLOT][2], zf, 0, 0, 0); \
        f32x4 c3 = __builtin_amdgcn_mfma_f32_16x16x32_f16(A3, ring[SLOT][3], zf, 0, 0, 0); \
        f32x4 cs = __builtin_amdgcn_mfma_f32_16x16x32_f16(A0, A0, zf, 0, 0, 0); \
        cs = __builtin_amdgcn_mfma_f32_16x16x32_f16(A1, A1, cs, 0, 0, 0);     \
        cs = __builtin_amdgcn_mfma_f32_16x16x32_f16(A2, A2, cs, 0, 0, 0);     \
        cs = __builtin_amdgcn_mfma_f32_16x16x32_f16(A3, A3, cs, 0, 0, 0);     \
        float inv = 1.f / fmaxf(sqrtf(cs[0]), 1e-12f);                        \
        float y = c0[0] + c1[0] + c2[0] + c3[0];                              \
        float un = fmaxf(y, 0.f) * inv;                                       \
        if (q == 0) {                                                         \
          _Float16 nh = (_Float16)un;                                         \
          unsigned nb = (unsigned)__builtin_bit_cast(unsigned short, nh);     \
          if (SETN) nb |= 0x8000u;                                            \
          unsigned short* pubp = xb + NSLOT * 128 + col;                      \
          float o = unreg * inv;                                              \
          const int gt = c * TC_ + (TT);                                      \
          float* gp = (gt > 0) ? (outb + (size_t)(gt - 1) * D_) : dsink;      \
          asm volatile("global_store_short %0, %1, off sc0 sc1\n\t"           \
                       "global_store_dword %2, %3, off"                       \
                       :: "v"(pubp), "v"(nb), "v"(gp), "v"(o) : "memory");    \
        }                                                                     \
        const char* gd2 = Gw + (size_t)(((TT) + 4) & 15) * 32768;             \
        LDSLOT(SLOT, gd2);                                                    \
        unreg = un;                                                           \
      }                                                                       \
      asm volatile("s_barrier" ::: "memory");                                 \
    }

    for (int c = 0; c < NCH_; ++c) {
      if (tid == 0) {
        int gd = 0;
        while (__hip_atomic_load(&flags[c * 8 + (b >> 4) * 4 + p],
                                 __ATOMIC_RELAXED, __HIP_MEMORY_SCOPE_AGENT) < 16u) {
          __builtin_amdgcn_s_sleep(2);
          if (++gd > SPINCAP) break;
        }
        __threadfence();   // acquire: invalidate stale L1/L2 (buffer reuse)
      }
      __syncthreads();

      Gw = (const char*)tbase + (size_t)(c % NB) * CHB
         + (size_t)b * TC_ * 32768 + (size_t)W * 4096 + lane * 16;

      if (act) {
        LDSLOT(0, Gw + 0 * 32768);
        LDSLOT(1, Gw + 1 * 32768);
        LDSLOT(2, Gw + 2 * 32768);
        LDSLOT(3, Gw + 3 * 32768);
      }

      STEP(0, 12)  STEP(1, 14)  STEP(2, 16)  STEP(3, 18)
      STEP(4, 18)  STEP(5, 18)  STEP(6, 18)  STEP(7, 18)
      STEP(8, 18)  STEP(9, 18)  STEP(10, 18) STEP(11, 18)
      STEP(12, 18) STEP(13, 18) STEP(14, 18) STEP(15, 18)

      if (act) asm volatile("s_waitcnt vmcnt(0)" ::: "memory");
      __syncthreads();   // full drain before releasing the buffer
      if (tid == 0)
        __hip_atomic_fetch_add(&flags[512 + c], 1u, __ATOMIC_RELAXED,
                               __HIP_MEMORY_SCOPE_AGENT);
    }
#undef STEP
#undef LDSLOT

    // ---- epilogue: "step 512" exchange, then out[511] = u512/||u512|| ----
    {
      // poll slot (512&3)=0, expect SET (((512>>2)&1)==0)
      if (w == 0) {
        const unsigned* pga = (const unsigned*)((const char*)xb + 0 * 256 + pdw);
        unsigned v = 0; int gd = 0; const bool need = (lane < 48);
        for (;;) {
          asm volatile("global_load_dword %0, %1, off sc0 sc1\n\t"
                       "s_waitcnt vmcnt(0)" : "=v"(v) : "v"(pga) : "memory");
          bool ok = !need || ((((v >> 15) & 1u) == 1u) && (((v >> 31) & 1u) == 1u));
          if (__all(ok) || ++gd > SPINCAP) break;
        }
        if (need) {
          v &= 0x7fff7fffu;
          asm volatile("ds_write_b32 %0, %1" :: "v"(psb), "v"(v) : "memory");
        }
      } else if (act && q == 0) {
        _Float16 hf = (_Float16)unreg;
        unsigned hb = (unsigned)__builtin_bit_cast(unsigned short, hf);
        asm volatile("ds_write_b16 %0, %1" :: "v"(aOwn), "v"(hb) : "memory");
      }
      asm volatile("s_waitcnt lgkmcnt(0)\n\ts_barrier" ::: "memory");
      if (act) {
        f16x8 A0, A1, A2, A3;
        asm volatile(
          "ds_read_b128 %0, %4 offset:0\n\t"
          "ds_read_b128 %1, %4 offset:64\n\t"
          "ds_read_b128 %2, %4 offset:128\n\t"
          "ds_read_b128 %3, %4 offset:192\n\t"
          "s_waitcnt lgkmcnt(0)"
          : "=v"(A0), "=v"(A1), "=v"(A2), "=v"(A3)
          : "v"(aA) : "memory");
        f32x4 cs = __builtin_amdgcn_mfma_f32_16x16x32_f16(A0, A0, zf, 0, 0, 0);
        cs = __builtin_amdgcn_mfma_f32_16x16x32_f16(A1, A1, cs, 0, 0, 0);
        cs = __builtin_amdgcn_mfma_f32_16x16x32_f16(A2, A2, cs, 0, 0, 0);
        cs = __builtin_amdgcn_mfma_f32_16x16x32_f16(A3, A3, cs, 0, 0, 0);
        float inv = 1.f / fmaxf(sqrtf(cs[0]), 1e-12f);
        if (q == 0) outb[(size_t)(T_ - 1) * D_] = unreg * inv;
      }
    }
  } else {
    // ======================= streaming gemm producer ========================
    _Float16* smA[2] = {(_Float16*)smem, (_Float16*)(smem + 32768)};
    _Float16* smB[2] = {(_Float16*)(smem + 16384), (_Float16*)(smem + 49152)};

    const int wm = w >> 2, wn = w & 3;          // 2x4 wave grid: 128m x 64n
    const int fm = lane & 15, fq = lane >> 4;
    const int sw = fq ^ ((fm >> 1) & 3);        // bank-conflict deswizzle
    const f32x4 zero = {0.f, 0.f, 0.f, 0.f};

    const int cA0 = tid, cA1 = tid + 512;
    const int rA0 = cA0 >> 2, rA1 = cA1 >> 2;
    const int kA0 = (cA0 & 3) ^ ((rA0 >> 1) & 3);  // swizzled k-slot (staging)
    const int kA1 = (cA1 & 3) ^ ((rA1 >> 1) & 3);

    const int TOT = NCH_ * 128;                 // 4096 tiles (128/chunk)

    for (int job = (int)blockIdx.x - 128; job < TOT; job += 128) {
      const int g    = job >> 7;
      const int tile = job & 127;
      const int bn = tile & 63;
      const int bm = tile >> 6;

      _Float16* trans = (_Float16*)((char*)tbase + (size_t)(g % NB) * CHB);
      const int t0g = g * TC_;

      const int mc0 = bm * 256 + rA0, mc1 = bm * 256 + rA1;
      const int bb0 = mc0 >> 4, bb1 = mc1 >> 4;
      const _Float16* gA0 = h16 + ((size_t)bb0 * T_ + t0g + (mc0 & 15)) * H_ + kA0 * 8;
      const _Float16* gA1 = h16 + ((size_t)bb1 * T_ + t0g + (mc1 & 15)) * H_ + kA1 * 8;
      const _Float16* gB0 = w2t + ((size_t)bn * 256 + rA0) * H_ + kA0 * 8;
      const _Float16* gB1 = w2t + ((size_t)bn * 256 + rA1) * H_ + kA1 * 8;
      _Float16* lA0[2] = {&smA[0][cA0 * 8], &smA[1][cA0 * 8]};
      _Float16* lA1[2] = {&smA[0][cA1 * 8], &smA[1][cA1 * 8]};
      _Float16* lB0[2] = {&smB[0][cA0 * 8], &smB[1][cA0 * 8]};
      _Float16* lB1[2] = {&smB[0][cA1 * 8], &smB[1][cA1 * 8]};

      f32x4 acc[8][4];
      #pragma unroll
      for (int i = 0; i < 8; ++i)
        #pragma unroll
        for (int j = 0; j < 4; ++j) acc[i][j] = zero;

      // prologue: stage kt=0 into half 0
      glds(gA0, lA0[0]);
      glds(gA1, lA1[0]);
      glds(gB0, lB0[0]);
      glds(gB1, lB1[0]);

      #pragma unroll
      for (int kt = 0; kt < 8; ++kt) {
        __syncthreads();   // implicit vmcnt(0): glds(kt) landed; half free
        if (kt < 7) {
          const int h2 = (kt + 1) & 1;
          glds(gA0 + (kt + 1) * 32, lA0[h2]);
          glds(gA1 + (kt + 1) * 32, lA1[h2]);
          glds(gB0 + (kt + 1) * 32, lB0[h2]);
          glds(gB1 + (kt + 1) * 32, lB1[h2]);
        }
        const int hh = kt & 1;
        const _Float16* bA = smA[hh];
        const _Float16* bB = smB[hh];
        f16x8 af[8], bf[4];
        #pragma unroll
        for (int mt = 0; mt < 8; ++mt)
          af[mt] = *(const f16x8*)&bA[(wm * 128 + mt * 16 + fm) * 32 + sw * 8];
        #pragma unroll
        for (int nt = 0; nt < 4; ++nt)
          bf[nt] = *(const f16x8*)&bB[(wn * 64 + nt * 16 + fm) * 32 + sw * 8];
        #pragma unroll
        for (int mt = 0; mt < 8; ++mt)
          #pragma unroll
          for (int nt = 0; nt < 4; ++nt)
            acc[mt][nt] = __builtin_amdgcn_mfma_f32_16x16x32_f16(bf[nt], af[mt], acc[mt][nt], 0, 0, 0);
      }

      // bias decode (b2 direct, L2-hit) — hoisted before the gating wait
      const int colbase = bn * 256 + wn * 64;
      float bias[4][4];
      #pragma unroll
      for (int nt = 0; nt < 4; ++nt) {
        #pragma unroll
        for (int j = 0; j < 4; ++j) {
          int pc = colbase + nt * 16 + fq * 4 + j;
          int ii = ((pc >> 9) & 3) * 32 + ((pc >> 7) & 3) * 8 + (pc & 7);
          int jj = (pc >> 11) * 16 + ((pc >> 3) & 15);
          bias[nt][j] = b2[ii * 128 + jj];
        }
      }

      // back-pressure (buffer reuse) — gate only the overwrite
      if (g >= NB) {
        if (tid == 0) {
          int gd = 0;
          while (__hip_atomic_load(&flags[512 + g - NB], __ATOMIC_RELAXED,
                                   __HIP_MEMORY_SCOPE_AGENT) < 128u) {
            __builtin_amdgcn_s_sleep(8);
            if (++gd > SPINCAP) break;
          }
        }
        __syncthreads();
      }

      // epilogue: swapped-operand layout -> lane fm holds rows, 4 consec cols
      #pragma unroll
      for (int nt = 0; nt < 4; ++nt) {
        const int cb = nt * 16 + fq * 4;
        #pragma unroll
        for (int mt = 0; mt < 8; ++mt) {
          const long row = bm * 256 + wm * 128 + mt * 16 + fm;
          f16x4 v;
          #pragma unroll
          for (int j = 0; j < 4; ++j)
            v[j] = (_Float16)(acc[mt][nt][j] + bias[nt][j]);
          *(f16x4*)&trans[row * (long)N_ + colbase + cb] = v;
        }
      }
      __syncthreads();   // per-wave vmcnt(0): all stores drained
      if (tid == 0) {
        __threadfence();  // wbl2: cross-XCD release
        __hip_atomic_fetch_add(&flags[g * 8 + bm * 4 + (bn >> 4)], 1u,
                               __ATOMIC_RELAXED, __HIP_MEMORY_SCOPE_AGENT);
      }
    }
  }
}

// ---------------------------------------------------------------------------
extern "C" void kernel_launch(void* const* d_in, const int* in_sizes, int n_in,
                              void* d_out, int out_size, void* d_ws, size_t ws_size,
                              hipStream_t stream) {
  const float* actions = (const float*)d_in[0];   // [32,512,64]
  const float* init_s  = (const float*)d_in[1];   // [128]
  const float* w1      = (const float*)d_in[2];   // [64,256]
  const float* b1      = (const float*)d_in[3];   // [256]
  const float* w2      = (const float*)d_in[4];   // [256,16384]
  const float* b2      = (const float*)d_in[5];   // [16384]
  float* out = (float*)d_out;                     // [32,512,128]

  uint8_t* ws = (uint8_t*)d_ws;
  _Float16* w2t = (_Float16*)ws;                          // 8 MB
  _Float16* h16 = (_Float16*)(ws + ((size_t)8 << 20));    // 8 MB
  const size_t tb_off = (size_t)16 << 20;
  _Float16* tbase = (_Float16*)(ws + tb_off);

  // deepest chunk ring that fits (aux = dummy 64KB + flags 4KB + xch 32KB)
  const size_t aux = 65536 + 4096 + 32768;
  int NB = 2;
  if (tb_off + 4 * CHB + aux <= ws_size) NB = 4;
  else if (tb_off + 3 * CHB + aux <= ws_size) NB = 3;

  float*    dummyws = (float*)(ws + tb_off + (size_t)NB * CHB);
  unsigned* flags   = (unsigned*)(ws + tb_off + (size_t)NB * CHB + 65536);
  unsigned* xchw    = (unsigned*)(ws + tb_off + (size_t)NB * CHB + 65536 + 4096);

  prep_kernel<<<1536, 256, 0, stream>>>(w2, w2t, actions, w1, b1, h16,
                                        flags, xchw);
  fused_kernel<<<256, 512, 0, stream>>>(h16, w2t, b2, tbase, init_s,
                                        out, dummyws, flags,
                                        (unsigned short*)xchw, NB);
}

// Round 9
// 579.531 us; speedup vs baseline: 1.6851x; 1.5920x over previous
//
#include <hip/hip_runtime.h>
#include <stdint.h>
#include <math.h>

// ---------------------------------------------------------------------------
// PathIntegration: h = relu(actions@w1+b1); trans = (h@w2+b2) -> [B,T,D,D]
// s_{t+1} = l2norm(relu(s_t @ trans_t)); output ys[B,T,D] (f32)
// B=32 T=512 A=64 H=256 D=128
// Round 17 = r12 (proven, 666us) with the coherence scheme swapped to
// fence-free write-through (r13 protocol MINUS the fatal nt):
//  - trans producer stores:  sc1       (write-through to IC; nothing dirty,
//                                       no wbl2 fence needed, L2 not nuked)
//  - trans consumer loads:   sc0 sc1   (bypass L1/L2 -> IC ~600cyc, NOT
//                                       HBM ~900; ring depth 4 = 4.5us of
//                                       lookahead >> IC latency)
//  - NO __threadfence() anywhere: r12's rec-side acquire fence was 1024
//    XCD-L2 invalidations/run (one per 4.5us/XCD), nuking co-resident gemm
//    blocks' cached w2t/h16 -> the 418MB FETCH_SIZE and the 18us period.
//  - flag adds RELEASE (cheap: no dirty lines), polls RELAXED (r12-proven).
// Everything else byte-identical to r12: k-loop LDS dbuf gemm, swizzle,
// f16x4 epilogue, register-ring rec with vmcnt 12/13/14/15/16 schedule.
// ---------------------------------------------------------------------------

typedef _Float16 f16x8 __attribute__((ext_vector_type(8)));
typedef _Float16 f16x4 __attribute__((ext_vector_type(4)));
typedef float    f32x4 __attribute__((ext_vector_type(4)));

#define B_  32
#define T_  512
#define A_  64
#define H_  256
#define D_  128
#define N_  (D_ * D_)      // 16384
#define M_  (B_ * T_)      // 16384
#define TC_ 16
#define NCH_ (T_ / TC_)    // 32
#define MT_ 2              // 256-row groups per chunk
#define CHB ((size_t)TC_ << 20)   // 16 MB per chunk buffer

__device__ inline void glds(const void* g, void* l) {
  __builtin_amdgcn_global_load_lds(
      (__attribute__((address_space(1))) void*)g,
      (__attribute__((address_space(3))) void*)l, 16, 0, 0);
}

// ---------------- prep: w2 cast+transpose+permute, h, flags ------------------
// w2t permute: orig col n -> T entry (i=n>>7, j=n&127); position
// p = (j>>4)<<11 | (i>>5)<<9 | ((i>>3)&3)<<7 | (j&15)<<3 | (i&7)
// per (b,t) 32KB slab is wave-major, frag-major, lane-direct.
__global__ __launch_bounds__(256) void prep_kernel(
    const float* __restrict__ w2, _Float16* __restrict__ w2t,
    const float* __restrict__ actions, const float* __restrict__ w1,
    const float* __restrict__ b1, _Float16* __restrict__ h16,
    unsigned* __restrict__ flags) {
  __shared__ __align__(16) char psm[40960];
  const int t = threadIdx.x;
  if (blockIdx.x < 1024) {
    // ---------------- w2cast part ----------------
    if (blockIdx.x == 0) {
      #pragma unroll
      for (int i = 0; i < 4; ++i) flags[t + i * 256] = 0u;
    }
    float (*tile)[65] = (float(*)[65])psm;
    const int n0 = (blockIdx.x & 255) * 64, k0 = (blockIdx.x >> 8) * 64;
    const int nn = t & 63, kg = t >> 6;
    #pragma unroll
    for (int r = 0; r < 16; ++r) {
      int k = kg * 16 + r;
      tile[k][nn] = w2[(size_t)(k0 + k) * N_ + n0 + nn];
    }
    __syncthreads();
    const int kk = t & 63, ng = t >> 6;
    #pragma unroll
    for (int r = 0; r < 16; ++r) {
      int n = ng * 16 + r;
      int ngl = n0 + n;
      int i = ngl >> 7, j = ngl & 127;
      int p = ((j >> 4) << 11) | ((i >> 5) << 9) | (((i >> 3) & 3) << 7)
            | ((j & 15) << 3) | (i & 7);
      w2t[(size_t)p * H_ + k0 + kk] = (_Float16)tile[kk][n];
    }
  } else {
    // ---------------- h = relu(actions@w1+b1) ----------------
    float* w1s = (float*)psm;             // 32*256 f32
    float* acts = (float*)(psm + 32768);  // 32*64 f32
    const size_t row0 = (size_t)(blockIdx.x - 1024) * 32;

    #pragma unroll
    for (int i = 0; i < 8; ++i) acts[t + i * 256] = actions[row0 * A_ + t + i * 256];

    float acc[32];
    float bj = b1[t];
    #pragma unroll
    for (int r = 0; r < 32; ++r) acc[r] = bj;

    for (int half = 0; half < 2; ++half) {
      __syncthreads();
      #pragma unroll
      for (int i = 0; i < 32; ++i) w1s[t + i * 256] = w1[half * 32 * 256 + t + i * 256];
      __syncthreads();
      #pragma unroll
      for (int r = 0; r < 32; ++r) {
        float a = acc[r];
        #pragma unroll
        for (int k = 0; k < 32; ++k)
          a += acts[r * 64 + half * 32 + k] * w1s[k * 256 + t];
        acc[r] = a;
      }
    }
    #pragma unroll
    for (int r = 0; r < 32; ++r)
      h16[(row0 + r) * H_ + t] = (_Float16)fmaxf(acc[r], 0.f);
  }
}

// ---------------- fused pipeline: rec blocks 0..31, gemm 32..255 -------------
__global__ __launch_bounds__(512, 2) void fused_kernel(
    const _Float16* __restrict__ h16, const _Float16* __restrict__ w2t,
    const float* __restrict__ b2, _Float16* __restrict__ tbase,
    const float* __restrict__ init_s, float* __restrict__ out,
    float* __restrict__ dummyws, unsigned* __restrict__ flags, int NB) {

  // gemm blocks use all 64KB (A/B double-buffer). rec blocks (disjoint)
  // overlap: sb0 @0 (256B), sb1 @256 (256B), red @512 (32B).
  __shared__ __align__(16) char smem[65536];
  const int tid  = threadIdx.x;
  const int lane = tid & 63;
  const int w    = tid >> 6;

  if (blockIdx.x < 32) {
    // ======================= recurrence block ===============================
    const int b  = blockIdx.x;
    const int n16 = lane & 15, q = lane >> 4;
    const int col = w * 16 + n16;
    float* red = (float*)(smem + 512);
    _Float16* sb0p = (_Float16*)smem;

    // ---- init s_0 once (state persists in LDS/regs across chunks) ----
    float v0 = 0.f;
    if (tid < 128) {
      v0 = init_s[tid];
      float ss = v0 * v0;
      #pragma unroll
      for (int off = 32; off > 0; off >>= 1) ss += __shfl_xor(ss, off);
      if (lane == 0) red[w] = ss;
    }
    __syncthreads();
    if (tid < 128) {
      float inv0 = 1.f / fmaxf(sqrtf(red[0] + red[1]), 1e-12f);
      sb0p[tid] = (_Float16)(v0 * inv0);
    }
    __syncthreads();
    float uprev = (float)sb0p[col];

    const unsigned sbase = (unsigned)(size_t)(__attribute__((address_space(3))) char*)smem;
    const unsigned aA0 = sbase + 0   + q * 16;   // step par 0 reads sb0
    const unsigned aA1 = sbase + 256 + q * 16;   // step par 1 reads sb1
    const unsigned aW0 = sbase + 256 + col * 2;  // step par 0 writes sb1
    const unsigned aW1 = sbase + 0   + col * 2;  // step par 1 writes sb0
    float* outb = out + (size_t)b * T_ * D_ + col;
    float* dsink = dummyws + b * 128 + col;
    const int grp = b >> 4;

    f16x8 ring[4][4];
    const f32x4 zf = {0.f, 0.f, 0.f, 0.f};

#define LDSLOT(S, P)                                                          \
    asm volatile("global_load_dwordx4 %0, %4, off sc0 sc1\n\t"                \
                 "global_load_dwordx4 %1, %4, off offset:1024 sc0 sc1\n\t"    \
                 "global_load_dwordx4 %2, %4, off offset:2048 sc0 sc1\n\t"    \
                 "global_load_dwordx4 %3, %4, off offset:3072 sc0 sc1"        \
                 : "=v"(ring[S][0]), "=v"(ring[S][1]),                        \
                   "=v"(ring[S][2]), "=v"(ring[S][3])                         \
                 : "v"(P) : "memory")

#define STEP(TT, PAR, SPAR, WAITN)                                            \
    {                                                                         \
      const int tt = (TT);                                                    \
      f16x8 A0, A1, A2, A3;                                                   \
      asm volatile(                                                           \
        "s_waitcnt vmcnt(" #WAITN ")\n\t"                                     \
        "ds_read_b128 %0, %8 offset:0\n\t"                                    \
        "ds_read_b128 %1, %8 offset:64\n\t"                                   \
        "ds_read_b128 %2, %8 offset:128\n\t"                                  \
        "ds_read_b128 %3, %8 offset:192\n\t"                                  \
        "s_waitcnt lgkmcnt(0)"                                                \
        : "=v"(A0), "=v"(A1), "=v"(A2), "=v"(A3),                             \
          "+v"(ring[PAR][0]), "+v"(ring[PAR][1]),                             \
          "+v"(ring[PAR][2]), "+v"(ring[PAR][3])                              \
        : "v"(aA##SPAR) : "memory");                                          \
      f32x4 c0 = __builtin_amdgcn_mfma_f32_16x16x32_f16(A0, ring[PAR][0], zf, 0, 0, 0); \
      f32x4 c1 = __builtin_amdgcn_mfma_f32_16x16x32_f16(A1, ring[PAR][1], zf, 0, 0, 0); \
      f32x4 c2 = __builtin_amdgcn_mfma_f32_16x16x32_f16(A2, ring[PAR][2], zf, 0, 0, 0); \
      f32x4 c3 = __builtin_amdgcn_mfma_f32_16x16x32_f16(A3, ring[PAR][3], zf, 0, 0, 0); \
      f32x4 cs = __builtin_amdgcn_mfma_f32_16x16x32_f16(A0, A0, zf, 0, 0, 0); \
      cs = __builtin_amdgcn_mfma_f32_16x16x32_f16(A1, A1, cs, 0, 0, 0);       \
      cs = __builtin_amdgcn_mfma_f32_16x16x32_f16(A2, A2, cs, 0, 0, 0);       \
      cs = __builtin_amdgcn_mfma_f32_16x16x32_f16(A3, A3, cs, 0, 0, 0);       \
      const char* gd = Gw + (size_t)((tt + 4) & 15) * 32768;                  \
      LDSLOT(PAR, gd);                                                        \
      float ssp = cs[0];                                                      \
      float inv = 1.f / fmaxf(sqrtf(ssp), 1e-12f);                            \
      float y = c0[0] + c1[0] + c2[0] + c3[0];                                \
      float un = fmaxf(y, 0.f) * inv;                                         \
      float o = uprev * inv;                                                  \
      uprev = un;                                                             \
      _Float16 hv = (_Float16)un;                                             \
      const int gt = t0 + tt;                                                 \
      float* gp = (gt > 0) ? (outb + (size_t)(gt - 1) * D_) : dsink;          \
      asm volatile("ds_write_b16 %0, %1\n\t"                                  \
                   "global_store_dword %2, %3, off"                           \
                   :: "v"(aW##SPAR), "v"(hv), "v"(gp), "v"(o) : "memory");    \
      asm volatile("s_waitcnt lgkmcnt(0)\n\ts_barrier" ::: "memory");         \
    }

    for (int c = 0; c < NCH_; ++c) {
      if (tid == 0) {
        while (__hip_atomic_load(&flags[c * MT_ + grp], __ATOMIC_RELAXED,
                                 __HIP_MEMORY_SCOPE_AGENT) < 64u)
          __builtin_amdgcn_s_sleep(8);
        // no fence: trans loads below bypass L1/L2 (sc0 sc1) -> no staleness
      }
      __syncthreads();

      const char* trans = (const char*)tbase + (size_t)(c % NB) * CHB;
      const char* Gw = trans + (size_t)b * TC_ * 32768 + w * 4096 + lane * 16;
      const int t0 = c * TC_;

      LDSLOT(0, Gw + 0 * 32768);
      LDSLOT(1, Gw + 1 * 32768);
      LDSLOT(2, Gw + 2 * 32768);
      LDSLOT(3, Gw + 3 * 32768);

      STEP(0, 0, 0, 12)
      STEP(1, 1, 1, 13)
      STEP(2, 2, 0, 14)
      STEP(3, 3, 1, 15)
      for (int tt0 = 4; tt0 < TC_; tt0 += 4) {
        STEP(tt0,     0, 0, 16)
        STEP(tt0 + 1, 1, 1, 16)
        STEP(tt0 + 2, 2, 0, 16)
        STEP(tt0 + 3, 3, 1, 16)
      }
      asm volatile("s_waitcnt vmcnt(0)" ::: "memory");
      __syncthreads();   // all waves' loads drained before releasing buffer
      if (tid == 0)
        __hip_atomic_fetch_add(&flags[512 + c], 1u, __ATOMIC_RELEASE,
                               __HIP_MEMORY_SCOPE_AGENT);
    }
#undef STEP
#undef LDSLOT

    // ---- final epilogue: state in sb0; write out[T-1] ----
    {
      float x = 0.f;
      if (lane < 16) x = (float)((_Float16*)smem)[col];
      float ss2 = x * x;
      ss2 += __shfl_xor(ss2, 1);
      ss2 += __shfl_xor(ss2, 2);
      ss2 += __shfl_xor(ss2, 4);
      ss2 += __shfl_xor(ss2, 8);
      if (lane == 0) red[w] = ss2;
      __syncthreads();
      float tot = 0.f;
      #pragma unroll
      for (int g = 0; g < 8; ++g) tot += red[g];
      float inv = 1.f / fmaxf(sqrtf(tot), 1e-12f);
      if (lane < 16) outb[(size_t)(T_ - 1) * D_] = uprev * inv;
    }
  } else {
    // ======================= streaming gemm producer ========================
    _Float16* smA[2] = {(_Float16*)smem, (_Float16*)(smem + 32768)};
    _Float16* smB[2] = {(_Float16*)(smem + 16384), (_Float16*)(smem + 49152)};

    const int wm = w >> 2, wn = w & 3;          // 2x4 wave grid: 128m x 64n
    const int fm = lane & 15, fq = lane >> 4;
    const int sw = fq ^ ((fm >> 1) & 3);        // bank-conflict deswizzle
    const f32x4 zero = {0.f, 0.f, 0.f, 0.f};

    const int cA0 = tid, cA1 = tid + 512;
    const int rA0 = cA0 >> 2, rA1 = cA1 >> 2;
    const int kA0 = (cA0 & 3) ^ ((rA0 >> 1) & 3);  // swizzled k-slot (staging)
    const int kA1 = (cA1 & 3) ^ ((rA1 >> 1) & 3);

    const int TOT = NCH_ * 128;                 // 4096 tiles (128/chunk)

    for (int job = (int)blockIdx.x - 32; job < TOT; job += 224) {
      const int g    = job >> 7;
      const int tile = job & 127;
      const int bn = tile & 63;
      const int bm = tile >> 6;

      _Float16* trans = (_Float16*)((char*)tbase + (size_t)(g % NB) * CHB);
      const int t0g = g * TC_;

      const int mc0 = bm * 256 + rA0, mc1 = bm * 256 + rA1;
      const int bb0 = mc0 >> 4, bb1 = mc1 >> 4;
      const _Float16* gA0 = h16 + ((size_t)bb0 * T_ + t0g + (mc0 & 15)) * H_ + kA0 * 8;
      const _Float16* gA1 = h16 + ((size_t)bb1 * T_ + t0g + (mc1 & 15)) * H_ + kA1 * 8;
      const _Float16* gB0 = w2t + ((size_t)bn * 256 + rA0) * H_ + kA0 * 8;
      const _Float16* gB1 = w2t + ((size_t)bn * 256 + rA1) * H_ + kA1 * 8;
      _Float16* lA0[2] = {&smA[0][cA0 * 8], &smA[1][cA0 * 8]};
      _Float16* lA1[2] = {&smA[0][cA1 * 8], &smA[1][cA1 * 8]};
      _Float16* lB0[2] = {&smB[0][cA0 * 8], &smB[1][cA0 * 8]};
      _Float16* lB1[2] = {&smB[0][cA1 * 8], &smB[1][cA1 * 8]};

      f32x4 acc[8][4];
      #pragma unroll
      for (int i = 0; i < 8; ++i)
        #pragma unroll
        for (int j = 0; j < 4; ++j) acc[i][j] = zero;

      // prologue: stage kt=0 into half 0
      glds(gA0, lA0[0]);
      glds(gA1, lA1[0]);
      glds(gB0, lB0[0]);
      glds(gB1, lB1[0]);

      #pragma unroll
      for (int kt = 0; kt < 8; ++kt) {
        __syncthreads();   // implicit vmcnt(0): glds(kt) landed; half free
        if (kt < 7) {
          const int h2 = (kt + 1) & 1;
          glds(gA0 + (kt + 1) * 32, lA0[h2]);
          glds(gA1 + (kt + 1) * 32, lA1[h2]);
          glds(gB0 + (kt + 1) * 32, lB0[h2]);
          glds(gB1 + (kt + 1) * 32, lB1[h2]);
        }
        const int hh = kt & 1;
        const _Float16* bA = smA[hh];
        const _Float16* bB = smB[hh];
        f16x8 af[8], bf[4];
        #pragma unroll
        for (int mt = 0; mt < 8; ++mt)
          af[mt] = *(const f16x8*)&bA[(wm * 128 + mt * 16 + fm) * 32 + sw * 8];
        #pragma unroll
        for (int nt = 0; nt < 4; ++nt)
          bf[nt] = *(const f16x8*)&bB[(wn * 64 + nt * 16 + fm) * 32 + sw * 8];
        #pragma unroll
        for (int mt = 0; mt < 8; ++mt)
          #pragma unroll
          for (int nt = 0; nt < 4; ++nt)
            acc[mt][nt] = __builtin_amdgcn_mfma_f32_16x16x32_f16(bf[nt], af[mt], acc[mt][nt], 0, 0, 0);
      }

      // bias decode (b2 direct, L2-hit) — hoisted before the gating wait
      const int colbase = bn * 256 + wn * 64;
      float bias[4][4];
      #pragma unroll
      for (int nt = 0; nt < 4; ++nt) {
        #pragma unroll
        for (int j = 0; j < 4; ++j) {
          int p = colbase + nt * 16 + fq * 4 + j;
          int ii = ((p >> 9) & 3) * 32 + ((p >> 7) & 3) * 8 + (p & 7);
          int jj = (p >> 11) * 16 + ((p >> 3) & 15);
          bias[nt][j] = b2[ii * 128 + jj];
        }
      }

      // back-pressure (buffer reuse) — gate only the overwrite
      if (g >= NB) {
        if (tid == 0) {
          while (__hip_atomic_load(&flags[512 + g - NB], __ATOMIC_RELAXED,
                                   __HIP_MEMORY_SCOPE_AGENT) < 32u)
            __builtin_amdgcn_s_sleep(8);
        }
        __syncthreads();
      }

      // epilogue: swapped-operand layout -> lane fm holds rows, 4 consec cols
      // stores sc1 (write-through, NO nt): IC-visible at vmcnt(0), no dirty
      // L2, no pollution of w2t/h16 working set, no wbl2 fence needed.
      #pragma unroll
      for (int nt = 0; nt < 4; ++nt) {
        const int cb = nt * 16 + fq * 4;
        #pragma unroll
        for (int mt = 0; mt < 8; ++mt) {
          const long row = bm * 256 + wm * 128 + mt * 16 + fm;
          f16x4 v;
          #pragma unroll
          for (int j = 0; j < 4; ++j)
            v[j] = (_Float16)(acc[mt][nt][j] + bias[nt][j]);
          _Float16* sp = &trans[row * (long)N_ + colbase + cb];
          asm volatile("global_store_dwordx2 %0, %1, off sc1"
                       :: "v"(sp), "v"(v) : "memory");
        }
      }
      __syncthreads();   // implicit vmcnt(0): sc1 stores accepted at IC
      if (tid == 0) {
        __hip_atomic_fetch_add(&flags[g * MT_ + bm], 1u, __ATOMIC_RELEASE,
                               __HIP_MEMORY_SCOPE_AGENT);
      }
    }
  }
}

// ---------------------------------------------------------------------------
extern "C" void kernel_launch(void* const* d_in, const int* in_sizes, int n_in,
                              void* d_out, int out_size, void* d_ws, size_t ws_size,
                              hipStream_t stream) {
  const float* actions = (const float*)d_in[0];   // [32,512,64]
  const float* init_s  = (const float*)d_in[1];   // [128]
  const float* w1      = (const float*)d_in[2];   // [64,256]
  const float* b1      = (const float*)d_in[3];   // [256]
  const float* w2      = (const float*)d_in[4];   // [256,16384]
  const float* b2      = (const float*)d_in[5];   // [16384]
  float* out = (float*)d_out;                     // [32,512,128]

  uint8_t* ws = (uint8_t*)d_ws;
  _Float16* w2t = (_Float16*)ws;                          // 8 MB
  _Float16* h16 = (_Float16*)(ws + ((size_t)8 << 20));    // 8 MB
  const size_t tb_off = (size_t)16 << 20;
  _Float16* tbase = (_Float16*)(ws + tb_off);

  // deepest chunk ring that fits (aux = 64KB dummy sink + 4KB flags after it)
  const size_t aux = 65536 + 4096;
  int NB = 2;
  if (tb_off + 4 * CHB + aux <= ws_size) NB = 4;
  else if (tb_off + 3 * CHB + aux <= ws_size) NB = 3;

  float*    dummyws = (float*)(ws + tb_off + (size_t)NB * CHB);
  unsigned* flags   = (unsigned*)(ws + tb_off + (size_t)NB * CHB + 65536);

  prep_kernel<<<1536, 256, 0, stream>>>(w2, w2t, actions, w1, b1, h16, flags);
  fused_kernel<<<256, 512, 0, stream>>>(h16, w2t, b2, tbase, init_s,
                                        out, dummyws, flags, NB);
}